// Round 17
// baseline (186.124 us; speedup 1.0000x reference)
//
#include <hip/hip_runtime.h>
#include <cstdint>
#include <cstddef>

typedef unsigned short ushort_t;
typedef short bf16x8 __attribute__((ext_vector_type(8)));
typedef float f32x4 __attribute__((ext_vector_type(4)));

#define N_NODES 2048
#define E_EDGES 32768

// ---------------- canonical bf16 small-tensor buffer (ushort elements) ----------------
constexpr int SMALL_TOTAL = 72128;
constexpr int OFS_T1B1 = 6144;
constexpr int OFS_T1B2 = 12352;
constexpr int OFS_T1B3 = 18560;
constexpr int OFS_CHB  = 30912;
constexpr int OFS_T2B1 = 43264;
constexpr int OFS_T2B2 = 55616;
constexpr int OFS_T2B3 = 67968;
constexpr int OFS_GAM  = 68032;
constexpr int OFS_BET  = 70080;

// ---------------- device-global scratch ----------------
// INVARIANT: g_deg / g_cnt / g_cur / g_done are ZERO at kernel_launch entry.
// .bss zero-init covers the first call; prop_kernel<0> (stream-ordered after
// their last use) re-zeros them for the next call.
__device__ __align__(16) ushort_t g_t1b [3670016];   // (2,14,2048,64) bf16
__device__ __align__(16) ushort_t g_tx1b[3670016];
__device__ __align__(16) ushort_t g_tx2b[3670016];
__device__ __align__(16) ushort_t g_t2b [3670016];
__device__ __align__(16) float    g_t3 [3145728];    // (2,12,2048,64) fp32
__device__ float    g_deg[N_NODES];
__device__ int      g_cnt[N_NODES];
__device__ int      g_cur[N_NODES];
__device__ int      g_done;
__device__ __align__(8) int2 g_csrp[E_EDGES];        // (col, w bits) packed
__device__ int      g_rowstart[N_NODES + 1];
__device__ __align__(16) ushort_t g_can[SMALL_TOTAL];
// MFMA B-fragment packed weights: [set][nt][kk][lane][j]
__device__ __align__(16) ushort_t g_wb1[18432];   // tconv1
__device__ __align__(16) ushort_t g_wb2[36864];   // tconv2
__device__ __align__(16) ushort_t g_wbc[12288];   // cheb

// ---------------- helpers ----------------
__device__ __forceinline__ float bfu(ushort_t u) { return __uint_as_float(((unsigned)u) << 16); }
__device__ __forceinline__ ushort_t f2bf(float f) {
    unsigned u = __float_as_uint(f);
    u = u + 0x7fffu + ((u >> 16) & 1u);
    return (ushort_t)(u >> 16);
}
__device__ __forceinline__ float ldin(const void* p, int i, bool isbf) {
    return isbf ? bfu(((const ushort_t*)p)[i]) : ((const float*)p)[i];
}
#define BF16_ONES_PAIR 0x3F803F80u

struct SmallPtrs { const void* p[16]; };
struct WPtrs { const void* p[7]; };  // t1w1,t1w2,t1w3,t2w1,t2w2,t2w3,chW

// ---------------- setup_a: edge_count+inline scan (0..127) + convert_small (128..409) + repack (410..673) ----------------
// The LAST count block to finish (device-scope done counter) performs the rowstart
// prefix scan inline, reading g_cnt via atomic-reads (coherent point — G16-safe).
__global__ void setup_a_kernel(const int* __restrict__ ei, const void* __restrict__ ew,
                               SmallPtrs sp, WPtrs wp, const unsigned* __restrict__ gam) {
    __shared__ int part[256];
    __shared__ int pre[256];
    __shared__ int lastflag;
    const bool isbf = (gam[0] == BF16_ONES_PAIR);
    int blk = blockIdx.x;
    if (blk < 128) {
        int e = blk * 256 + threadIdx.x;
        int r = ei[e];
        int c = ei[E_EDGES + e];
        float w = (r == c) ? 0.f : ldin(ew, e, isbf);
        atomicAdd(&g_deg[r], w);
        atomicAdd(&g_cnt[r], 1);
        __threadfence();          // make this thread's count atomics globally visible
        __syncthreads();          // all threads in block have fenced
        if (threadIdx.x == 0) {
            int done = atomicAdd(&g_done, 1);
            lastflag = (done == 127) ? 1 : 0;
        }
        __syncthreads();
        if (!lastflag) return;
        // ---- inline scan by the last-finished count block ----
        int t = threadIdx.x;
        int base = t * 8;
        int cv[8];
        int ssum = 0;
#pragma unroll
        for (int i = 0; i < 8; ++i) {
            cv[i] = atomicAdd(&g_cnt[base + i], 0);   // atomic read: fresh at coherent point
            ssum += cv[i];
        }
        part[t] = ssum;
        __syncthreads();
        if (t == 0) {
            int a = 0;
            for (int i = 0; i < 256; ++i) { pre[i] = a; a += part[i]; }
        }
        __syncthreads();
        int a = pre[t];
#pragma unroll
        for (int i = 0; i < 8; ++i) { g_rowstart[base + i] = a; a += cv[i]; }
        if (t == 255) g_rowstart[N_NODES] = a;
        return;
    }
    if (blk < 410) {
        const int sizes[16] = {6144, 64, 6144, 64, 6144, 64, 12288, 64,
                               12288, 64, 12288, 64, 12288, 64, 2048, 2048};
        int idx = (blk - 128) * 256 + threadIdx.x;
        if (idx >= SMALL_TOTAL) return;
        int j = 0, local = idx;
        while (local >= sizes[j]) { local -= sizes[j]; ++j; }
        g_can[idx] = isbf ? ((const ushort_t*)sp.p[j])[local]
                          : f2bf(((const float*)sp.p[j])[local]);
        return;
    }
    // B frag for mfma_f32_16x16x32_bf16: lane holds B[n = lane&15][k = (lane>>4)*8 + j]
    int idx = (blk - 410) * 256 + threadIdx.x;   // 264 blocks -> 67584
    if (idx < 18432) {
        // tconv1: K = 96, k = ks*32 + ci, weight native [o][ci][ks]
        int j = idx & 7, lane = (idx >> 3) & 63, kk = (idx >> 9) % 3;
        int nt = (idx / 1536) & 3, set = idx / 6144;
        int o = nt * 16 + (lane & 15);
        int k = kk * 32 + (lane >> 4) * 8 + j;
        int ci = k & 31, ks = k >> 5;
        g_wb1[idx] = f2bf(ldin(wp.p[set], o * 96 + ci * 3 + ks, isbf));
    } else if (idx < 18432 + 36864) {
        // tconv2: K = 192, k = ks*64 + ci
        int t = idx - 18432;
        int j = t & 7, lane = (t >> 3) & 63, kk = (t >> 9) % 6;
        int nt = (t / 3072) & 3, set = t / 12288;
        int o = nt * 16 + (lane & 15);
        int k = kk * 32 + (lane >> 4) * 8 + j;
        int ci = k & 63, ks = k >> 6;
        g_wb2[t] = f2bf(ldin(wp.p[3 + set], o * 192 + ci * 3 + ks, isbf));
    } else {
        // cheb: K = 192, k = sec*64 + c, native [k][c][o]
        int t = idx - 18432 - 36864;
        int j = t & 7, lane = (t >> 3) & 63, kk = (t >> 9) % 6;
        int nt = t / 3072;
        int o = nt * 16 + (lane & 15);
        int k = kk * 32 + (lane >> 4) * 8 + j;
        int sec = k >> 6, c = k & 63;
        g_wbc[t] = f2bf(ldin(wp.p[6], sec * 4096 + c * 64 + o, isbf));
    }
}

// ---------------- gated temporal conv via MFMA (64-row blocks — R12-proven) ----------------
// LAYER 1: blocks 896..1023 perform the edge scatter (rowstart is visible across
// the setup_a -> tconv1 kernel boundary; tconv blocks don't touch CSR).
template <int LAYER>
__global__ __launch_bounds__(256) void tconv_mfma_kernel(const void* __restrict__ Xraw,
                                                         const int* __restrict__ ei,
                                                         const void* __restrict__ ew,
                                                         const unsigned* __restrict__ gam) {
    constexpr int CIN_  = (LAYER == 1) ? 32 : 64;
    constexpr int T_in  = (LAYER == 1) ? 16 : 14;
    constexpr int T_out = (LAYER == 1) ? 14 : 12;
    constexpr int KST   = (CIN_ * 3) / 32;          // 3 or 6
    constexpr int PADK  = (LAYER == 1) ? 104 : 200; // padded row stride (ushorts)
    constexpr int OB1 = (LAYER == 1) ? OFS_T1B1 : OFS_T2B1;
    constexpr int OB2 = (LAYER == 1) ? OFS_T1B2 : OFS_T2B2;
    constexpr int OB3 = (LAYER == 1) ? OFS_T1B3 : OFS_T2B3;

    if constexpr (LAYER == 1) {
        if (blockIdx.x >= 896) {
            bool isbf = (gam[0] == BF16_ONES_PAIR);
            int e = (blockIdx.x - 896) * 256 + threadIdx.x;
            int r = ei[e];
            int c = ei[E_EDGES + e];
            float w = (r == c) ? 0.f : ldin(ew, e, isbf);
            float dr = g_deg[r], dc = g_deg[c];
            float nr = dr > 0.f ? rsqrtf(dr) : 0.f;
            float nc = dc > 0.f ? rsqrtf(dc) : 0.f;
            int pos = atomicAdd(&g_cur[r], 1);
            g_csrp[g_rowstart[r] + pos] = make_int2(c, __float_as_int(-nr * w * nc));
            return;
        }
    }

    __shared__ ushort_t xs[64 * PADK];

    const int tid = threadIdx.x;
    const int lane = tid & 63;
    const int wv = tid >> 6;
    const int m0 = blockIdx.x * 64;
    const int n0 = m0 & (N_NODES - 1);
    const int s  = m0 >> 11;            // b*T_out + t (uniform in block)
    const int b  = s / T_out;
    const int t  = s - b * T_out;

#pragma unroll
    for (int ks = 0; ks < 3; ++ks) {
        if constexpr (LAYER == 1) {
            const bool isbf = (gam[0] == BF16_ONES_PAIR);
            const size_t elo = ((size_t)(b * T_in + t + ks) * N_NODES + n0) * 32;
            if (isbf) {
                const ushort4* src = (const ushort4*)((const ushort_t*)Xraw + elo);
                for (int i = tid; i < 512; i += 256) {
                    ushort4 v = src[i];
                    int row = i >> 3, c4 = i & 7;
                    *(ushort4*)&xs[row * PADK + ks * 32 + c4 * 4] = v;
                }
            } else {
                const float4* src = (const float4*)((const float*)Xraw + elo);
                for (int i = tid; i < 512; i += 256) {
                    float4 f = src[i];
                    ushort4 v;
                    v.x = f2bf(f.x); v.y = f2bf(f.y); v.z = f2bf(f.z); v.w = f2bf(f.w);
                    int row = i >> 3, c4 = i & 7;
                    *(ushort4*)&xs[row * PADK + ks * 32 + c4 * 4] = v;
                }
            }
        } else {
            const ushort4* src = (const ushort4*)(g_t2b +
                ((size_t)(b * T_in + t + ks) * N_NODES + n0) * 64);
            for (int i = tid; i < 1024; i += 256) {
                ushort4 v = src[i];
                int row = i >> 4, c4 = i & 15;
                *(ushort4*)&xs[row * PADK + ks * 64 + c4 * 4] = v;
            }
        }
    }
    __syncthreads();

    const ushort_t* WB = (LAYER == 1) ? g_wb1 : g_wb2;
    f32x4 acc[3][4];
#pragma unroll
    for (int st = 0; st < 3; ++st)
#pragma unroll
        for (int nt = 0; nt < 4; ++nt) acc[st][nt] = (f32x4){0.f, 0.f, 0.f, 0.f};

    const int arow = wv * 16 + (lane & 15);
    const int kofs = (lane >> 4) * 8;
#pragma unroll
    for (int kk = 0; kk < KST; ++kk) {
        bf16x8 av = *(const bf16x8*)&xs[arow * PADK + kk * 32 + kofs];
#pragma unroll
        for (int st = 0; st < 3; ++st)
#pragma unroll
            for (int nt = 0; nt < 4; ++nt) {
                bf16x8 bv = ((const bf16x8*)WB)[((st * 4 + nt) * KST + kk) * 64 + lane];
                acc[st][nt] = __builtin_amdgcn_mfma_f32_16x16x32_bf16(av, bv, acc[st][nt], 0, 0, 0);
            }
    }

    const int col = lane & 15;
    const int quad = lane >> 4;
#pragma unroll
    for (int nt = 0; nt < 4; ++nt) {
        int o = nt * 16 + col;
        float b1 = bfu(g_can[OB1 + o]);
        float b2 = bfu(g_can[OB2 + o]);
        float b3 = bfu(g_can[OB3 + o]);
#pragma unroll
        for (int reg = 0; reg < 4; ++reg) {
            int m = m0 + wv * 16 + quad * 4 + reg;
            float q = acc[1][nt][reg] + b2;
            float v = (acc[0][nt][reg] + b1) + 1.f / (1.f + expf(-q)) + (acc[2][nt][reg] + b3);
            v = v > 0.f ? v : 0.f;
            if constexpr (LAYER == 1) g_t1b[(size_t)m * 64 + o] = f2bf(v);
            else                      g_t3 [(size_t)m * 64 + o] = v;
        }
    }
}

// ---------------- graph propagation: 4-edge unroll (R15-proven), 7 slices/wave ----------------
// MODE 0 additionally re-zeros deg/cnt/cur/done for the next launch (blocks 0..7).
template <int MODE>
__global__ __launch_bounds__(256) void prop_kernel() {
    const ushort_t* __restrict__ src = (MODE == 0) ? g_t1b : g_tx1b;
    ushort_t* __restrict__ dst = (MODE == 0) ? g_tx1b : g_tx2b;
    const int n = blockIdx.x;
    const int c = threadIdx.x & 63;
    const int sg = threadIdx.x >> 6;
    const int beg = g_rowstart[n], end = g_rowstart[n + 1];
    const int s0 = sg * 7;

    if constexpr (MODE == 0) {
        if (blockIdx.x < 8) {
            int z = blockIdx.x * 256 + threadIdx.x;
            g_deg[z] = 0.f; g_cnt[z] = 0; g_cur[z] = 0;
            if (z == 0) g_done = 0;
        }
    }

    float acc[7];
#pragma unroll
    for (int j = 0; j < 7; ++j) acc[j] = 0.f;

    int e = beg;
    for (; e + 4 <= end; e += 4) {
        int2 p0 = g_csrp[e];
        int2 p1 = g_csrp[e + 1];
        int2 p2 = g_csrp[e + 2];
        int2 p3 = g_csrp[e + 3];
        float w0 = __int_as_float(p0.y);
        float w1 = __int_as_float(p1.y);
        float w2 = __int_as_float(p2.y);
        float w3 = __int_as_float(p3.y);
        size_t b0 = ((size_t)p0.x << 6) + c;
        size_t b1 = ((size_t)p1.x << 6) + c;
        size_t b2 = ((size_t)p2.x << 6) + c;
        size_t b3 = ((size_t)p3.x << 6) + c;
#pragma unroll
        for (int j = 0; j < 7; ++j) {
            size_t so = (size_t)(s0 + j) * (N_NODES * 64);
            float v0 = bfu(src[so + b0]);
            float v1 = bfu(src[so + b1]);
            float v2 = bfu(src[so + b2]);
            float v3 = bfu(src[so + b3]);
            acc[j] = fmaf(w0, v0, fmaf(w1, v1, fmaf(w2, v2, fmaf(w3, v3, acc[j]))));
        }
    }
    for (; e + 2 <= end; e += 2) {
        int2 p0 = g_csrp[e];
        int2 p1 = g_csrp[e + 1];
        float w0 = __int_as_float(p0.y);
        float w1 = __int_as_float(p1.y);
        size_t b0 = ((size_t)p0.x << 6) + c;
        size_t b1 = ((size_t)p1.x << 6) + c;
#pragma unroll
        for (int j = 0; j < 7; ++j) {
            size_t so = (size_t)(s0 + j) * (N_NODES * 64);
            float v0 = bfu(src[so + b0]);
            float v1 = bfu(src[so + b1]);
            acc[j] = fmaf(w1, v1, fmaf(w0, v0, acc[j]));
        }
    }
    if (e < end) {
        int2 p0 = g_csrp[e];
        float w0 = __int_as_float(p0.y);
        size_t b0 = ((size_t)p0.x << 6) + c;
#pragma unroll
        for (int j = 0; j < 7; ++j)
            acc[j] = fmaf(w0, bfu(src[(size_t)(s0 + j) * (N_NODES * 64) + b0]), acc[j]);
    }

#pragma unroll
    for (int j = 0; j < 7; ++j) {
        size_t off = ((size_t)(s0 + j) * N_NODES + n) * 64 + c;
        if constexpr (MODE == 0) dst[off] = f2bf(acc[j]);
        else                     dst[off] = f2bf(2.f * acc[j] - bfu(g_t1b[off]));
    }
}

// ---------------- Cheb combine via MFMA (64-row blocks — R12-proven) ----------------
__global__ __launch_bounds__(256) void cheb_mfma_kernel() {
    constexpr int PADK = 200;
    __shared__ ushort_t xs[64 * PADK];

    const int tid = threadIdx.x;
    const int lane = tid & 63;
    const int wv = tid >> 6;
    const int m0 = blockIdx.x * 64;

#pragma unroll
    for (int sec = 0; sec < 3; ++sec) {
        const ushort_t* sp = (sec == 0) ? g_t1b : (sec == 1) ? g_tx1b : g_tx2b;
        const ushort4* src = (const ushort4*)(sp + (size_t)m0 * 64);
        for (int i = tid; i < 1024; i += 256) {
            ushort4 v = src[i];
            int row = i >> 4, c4 = i & 15;
            *(ushort4*)&xs[row * PADK + sec * 64 + c4 * 4] = v;
        }
    }
    __syncthreads();

    f32x4 acc[4];
#pragma unroll
    for (int nt = 0; nt < 4; ++nt) acc[nt] = (f32x4){0.f, 0.f, 0.f, 0.f};

    const int arow = wv * 16 + (lane & 15);
    const int kofs = (lane >> 4) * 8;
#pragma unroll
    for (int kk = 0; kk < 6; ++kk) {
        bf16x8 av = *(const bf16x8*)&xs[arow * PADK + kk * 32 + kofs];
#pragma unroll
        for (int nt = 0; nt < 4; ++nt) {
            bf16x8 bv = ((const bf16x8*)g_wbc)[(nt * 6 + kk) * 64 + lane];
            acc[nt] = __builtin_amdgcn_mfma_f32_16x16x32_bf16(av, bv, acc[nt], 0, 0, 0);
        }
    }

    const int col = lane & 15;
    const int quad = lane >> 4;
#pragma unroll
    for (int nt = 0; nt < 4; ++nt) {
        int o = nt * 16 + col;
        float bias = bfu(g_can[OFS_CHB + o]);
#pragma unroll
        for (int reg = 0; reg < 4; ++reg) {
            int m = m0 + wv * 16 + quad * 4 + reg;
            float v = acc[nt][reg] + bias;
            g_t2b[(size_t)m * 64 + o] = f2bf(v > 0.f ? v : 0.f);
        }
    }
}

// ---------------- BatchNorm: stats + apply in ONE kernel, float4 I/O (R15-proven) ----------------
__global__ __launch_bounds__(256) void bn_fused_kernel(void* __restrict__ outp,
                                                       const unsigned* __restrict__ gam) {
    int n = blockIdx.x;
    int tid = threadIdx.x;
    int q = tid & 15;
    int g = tid >> 4;
    const bool two = (g < 8);

    size_t base0 = ((size_t)(g * N_NODES + n)) * 64 + q * 4;
    float4 v0 = *reinterpret_cast<const float4*>(&g_t3[base0]);
    float s1 = v0.x + v0.y + v0.z + v0.w;
    float s2 = v0.x * v0.x + v0.y * v0.y + v0.z * v0.z + v0.w * v0.w;
    size_t base1 = 0;
    float4 v1 = make_float4(0.f, 0.f, 0.f, 0.f);
    if (two) {
        base1 = ((size_t)((g + 16) * N_NODES + n)) * 64 + q * 4;
        v1 = *reinterpret_cast<const float4*>(&g_t3[base1]);
        s1 += v1.x + v1.y + v1.z + v1.w;
        s2 += v1.x * v1.x + v1.y * v1.y + v1.z * v1.z + v1.w * v1.w;
    }

    __shared__ float r1[256], r2[256];
    __shared__ float sc_s, sh_s;
    r1[tid] = s1;
    r2[tid] = s2;
    __syncthreads();
    for (int st = 128; st > 0; st >>= 1) {
        if (tid < st) { r1[tid] += r1[tid + st]; r2[tid] += r2[tid + st]; }
        __syncthreads();
    }
    if (tid == 0) {
        const float inv = 1.f / 1536.f;
        float mean = r1[0] * inv;
        float var  = r2[0] * inv - mean * mean;
        float rstd = rsqrtf(var + 1e-5f);
        float gm = bfu(g_can[OFS_GAM + n]), be = bfu(g_can[OFS_BET + n]);
        sc_s = rstd * gm;
        sh_s = be - mean * rstd * gm;
    }
    __syncthreads();
    float sc = sc_s, sh = sh_s;
    bool isbf = (gam[0] == BF16_ONES_PAIR);

    if (isbf) {
        ushort4 o0;
        o0.x = f2bf(v0.x * sc + sh); o0.y = f2bf(v0.y * sc + sh);
        o0.z = f2bf(v0.z * sc + sh); o0.w = f2bf(v0.w * sc + sh);
        *reinterpret_cast<ushort4*>((ushort_t*)outp + base0) = o0;
        if (two) {
            ushort4 o1;
            o1.x = f2bf(v1.x * sc + sh); o1.y = f2bf(v1.y * sc + sh);
            o1.z = f2bf(v1.z * sc + sh); o1.w = f2bf(v1.w * sc + sh);
            *reinterpret_cast<ushort4*>((ushort_t*)outp + base1) = o1;
        }
    } else {
        float4 o0 = make_float4(v0.x * sc + sh, v0.y * sc + sh, v0.z * sc + sh, v0.w * sc + sh);
        *reinterpret_cast<float4*>((float*)outp + base0) = o0;
        if (two) {
            float4 o1 = make_float4(v1.x * sc + sh, v1.y * sc + sh, v1.z * sc + sh, v1.w * sc + sh);
            *reinterpret_cast<float4*>((float*)outp + base1) = o1;
        }
    }
}

// ---------------- launch (7 dispatches) ----------------
extern "C" void kernel_launch(void* const* d_in, const int* in_sizes, int n_in,
                              void* d_out, int out_size, void* d_ws, size_t ws_size,
                              hipStream_t stream) {
    const void* X = d_in[0];
    const int* ei = (const int*)d_in[1];
    const void* ew = d_in[2];
    const unsigned* gam = (const unsigned*)d_in[17];

    SmallPtrs sp;
    for (int i = 0; i < 16; ++i) sp.p[i] = d_in[3 + i];
    WPtrs wp;
    wp.p[0] = d_in[3];  wp.p[1] = d_in[5];  wp.p[2] = d_in[7];    // tc1 w1..w3
    wp.p[3] = d_in[11]; wp.p[4] = d_in[13]; wp.p[5] = d_in[15];   // tc2 w1..w3
    wp.p[6] = d_in[9];                                            // cheb_w

    setup_a_kernel<<<674, 256, 0, stream>>>(ei, ew, sp, wp, gam); // count + inline scan + convert + repack

    tconv_mfma_kernel<1><<<1024, 256, 0, stream>>>(X, ei, ew, gam); // tconv1 + edge scatter

    prop_kernel<0><<<N_NODES, 256, 0, stream>>>();                // Tx1 = L t1 (+ re-zero)
    prop_kernel<1><<<N_NODES, 256, 0, stream>>>();                // Tx2 = 2 L Tx1 - t1
    cheb_mfma_kernel<<<896, 256, 0, stream>>>();                  // t2 = relu(sum Tx_k W_k + b)

    tconv_mfma_kernel<2><<<768, 256, 0, stream>>>(X, nullptr, nullptr, gam); // t2 -> t3 fp32

    bn_fused_kernel<<<N_NODES, 256, 0, stream>>>(d_out, gam);
}

// Round 18
// 177.499 us; speedup vs baseline: 1.0486x; 1.0486x over previous
//
#include <hip/hip_runtime.h>
#include <cstdint>
#include <cstddef>

typedef unsigned short ushort_t;
typedef short bf16x8 __attribute__((ext_vector_type(8)));
typedef float f32x4 __attribute__((ext_vector_type(4)));

#define N_NODES 2048
#define E_EDGES 32768

// ---------------- canonical bf16 small-tensor buffer (ushort elements) ----------------
constexpr int SMALL_TOTAL = 72128;
constexpr int OFS_T1B1 = 6144;
constexpr int OFS_T1B2 = 12352;
constexpr int OFS_T1B3 = 18560;
constexpr int OFS_CHB  = 30912;
constexpr int OFS_T2B1 = 43264;
constexpr int OFS_T2B2 = 55616;
constexpr int OFS_T2B3 = 67968;
constexpr int OFS_GAM  = 68032;
constexpr int OFS_BET  = 70080;

// ---------------- device-global scratch ----------------
// INVARIANT: g_deg / g_cnt / g_cur are ZERO at kernel_launch entry.
// .bss zero-init covers the first call; prop_kernel<0> (stream-ordered after
// their last use: count in setup_a, scan, scatter in tconv1) re-zeros them.
__device__ __align__(16) ushort_t g_t1b [3670016];   // (2,14,2048,64) bf16
__device__ __align__(16) ushort_t g_tx1b[3670016];
__device__ __align__(16) ushort_t g_tx2b[3670016];
__device__ __align__(16) ushort_t g_t2b [3670016];
__device__ __align__(16) float    g_t3 [3145728];    // (2,12,2048,64) fp32
__device__ float    g_deg[N_NODES];
__device__ int      g_cnt[N_NODES];
__device__ int      g_cur[N_NODES];
__device__ __align__(8) int2 g_csrp[E_EDGES];        // (col, w bits) packed
__device__ int      g_rowstart[N_NODES + 1];
__device__ __align__(16) ushort_t g_can[SMALL_TOTAL];
// MFMA B-fragment packed weights: [set][nt][kk][lane][j]
__device__ __align__(16) ushort_t g_wb1[18432];   // tconv1
__device__ __align__(16) ushort_t g_wb2[36864];   // tconv2
__device__ __align__(16) ushort_t g_wbc[12288];   // cheb

// ---------------- helpers ----------------
__device__ __forceinline__ float bfu(ushort_t u) { return __uint_as_float(((unsigned)u) << 16); }
__device__ __forceinline__ ushort_t f2bf(float f) {
    unsigned u = __float_as_uint(f);
    u = u + 0x7fffu + ((u >> 16) & 1u);
    return (ushort_t)(u >> 16);
}
__device__ __forceinline__ float ldin(const void* p, int i, bool isbf) {
    return isbf ? bfu(((const ushort_t*)p)[i]) : ((const float*)p)[i];
}
#define BF16_ONES_PAIR 0x3F803F80u

struct SmallPtrs { const void* p[16]; };
struct WPtrs { const void* p[7]; };  // t1w1,t1w2,t1w3,t2w1,t2w2,t2w3,chW

// ---------------- setup_a: edge_count (0..127) + convert_small (128..409) + repack (410..673) ----------------
// Repack reads RAW weight pointers (dtype-adaptive) — no dependency on the convert blocks.
__global__ void setup_a_kernel(const int* __restrict__ ei, const void* __restrict__ ew,
                               SmallPtrs sp, WPtrs wp, const unsigned* __restrict__ gam) {
    const bool isbf = (gam[0] == BF16_ONES_PAIR);
    int blk = blockIdx.x;
    if (blk < 128) {
        int e = blk * 256 + threadIdx.x;
        int r = ei[e];
        int c = ei[E_EDGES + e];
        float w = (r == c) ? 0.f : ldin(ew, e, isbf);
        atomicAdd(&g_deg[r], w);
        atomicAdd(&g_cnt[r], 1);
        return;
    }
    if (blk < 410) {
        const int sizes[16] = {6144, 64, 6144, 64, 6144, 64, 12288, 64,
                               12288, 64, 12288, 64, 12288, 64, 2048, 2048};
        int idx = (blk - 128) * 256 + threadIdx.x;
        if (idx >= SMALL_TOTAL) return;
        int j = 0, local = idx;
        while (local >= sizes[j]) { local -= sizes[j]; ++j; }
        g_can[idx] = isbf ? ((const ushort_t*)sp.p[j])[local]
                          : f2bf(((const float*)sp.p[j])[local]);
        return;
    }
    // B frag for mfma_f32_16x16x32_bf16: lane holds B[n = lane&15][k = (lane>>4)*8 + j]
    int idx = (blk - 410) * 256 + threadIdx.x;   // 264 blocks -> 67584
    if (idx < 18432) {
        // tconv1: K = 96, k = ks*32 + ci, weight native [o][ci][ks]
        int j = idx & 7, lane = (idx >> 3) & 63, kk = (idx >> 9) % 3;
        int nt = (idx / 1536) & 3, set = idx / 6144;
        int o = nt * 16 + (lane & 15);
        int k = kk * 32 + (lane >> 4) * 8 + j;
        int ci = k & 31, ks = k >> 5;
        g_wb1[idx] = f2bf(ldin(wp.p[set], o * 96 + ci * 3 + ks, isbf));
    } else if (idx < 18432 + 36864) {
        // tconv2: K = 192, k = ks*64 + ci
        int t = idx - 18432;
        int j = t & 7, lane = (t >> 3) & 63, kk = (t >> 9) % 6;
        int nt = (t / 3072) & 3, set = t / 12288;
        int o = nt * 16 + (lane & 15);
        int k = kk * 32 + (lane >> 4) * 8 + j;
        int ci = k & 63, ks = k >> 6;
        g_wb2[t] = f2bf(ldin(wp.p[3 + set], o * 192 + ci * 3 + ks, isbf));
    } else {
        // cheb: K = 192, k = sec*64 + c, native [k][c][o]
        int t = idx - 18432 - 36864;
        int j = t & 7, lane = (t >> 3) & 63, kk = (t >> 9) % 6;
        int nt = t / 3072;
        int o = nt * 16 + (lane & 15);
        int k = kk * 32 + (lane >> 4) * 8 + j;
        int sec = k >> 6, c = k & 63;
        g_wbc[t] = f2bf(ldin(wp.p[6], sec * 4096 + c * 64 + o, isbf));
    }
}

__global__ void scan_kernel() {
    __shared__ int part[256];
    __shared__ int pre[256];
    int t = threadIdx.x;
    int base = t * 8;
    int s = 0;
#pragma unroll
    for (int i = 0; i < 8; ++i) s += g_cnt[base + i];
    part[t] = s;
    __syncthreads();
    if (t == 0) {
        int a = 0;
        for (int i = 0; i < 256; ++i) { pre[i] = a; a += part[i]; }
    }
    __syncthreads();
    int a = pre[t];
#pragma unroll
    for (int i = 0; i < 8; ++i) { g_rowstart[base + i] = a; a += g_cnt[base + i]; }
    if (t == 255) g_rowstart[N_NODES] = a;
}

// ---------------- gated temporal conv via MFMA (64-row blocks — R12-proven) ----------------
// LAYER 1: blocks 896..1023 perform the edge scatter (needs scan; tconv blocks don't
// touch CSR, so co-scheduling is safe and overlaps the tiny scatter with the GEMM).
template <int LAYER>
__global__ __launch_bounds__(256) void tconv_mfma_kernel(const void* __restrict__ Xraw,
                                                         const int* __restrict__ ei,
                                                         const void* __restrict__ ew,
                                                         const unsigned* __restrict__ gam) {
    constexpr int CIN_  = (LAYER == 1) ? 32 : 64;
    constexpr int T_in  = (LAYER == 1) ? 16 : 14;
    constexpr int T_out = (LAYER == 1) ? 14 : 12;
    constexpr int KST   = (CIN_ * 3) / 32;          // 3 or 6
    constexpr int PADK  = (LAYER == 1) ? 104 : 200; // padded row stride (ushorts)
    constexpr int OB1 = (LAYER == 1) ? OFS_T1B1 : OFS_T2B1;
    constexpr int OB2 = (LAYER == 1) ? OFS_T1B2 : OFS_T2B2;
    constexpr int OB3 = (LAYER == 1) ? OFS_T1B3 : OFS_T2B3;

    if constexpr (LAYER == 1) {
        if (blockIdx.x >= 896) {
            bool isbf = (gam[0] == BF16_ONES_PAIR);
            int e = (blockIdx.x - 896) * 256 + threadIdx.x;
            int r = ei[e];
            int c = ei[E_EDGES + e];
            float w = (r == c) ? 0.f : ldin(ew, e, isbf);
            float dr = g_deg[r], dc = g_deg[c];
            float nr = dr > 0.f ? rsqrtf(dr) : 0.f;
            float nc = dc > 0.f ? rsqrtf(dc) : 0.f;
            int pos = atomicAdd(&g_cur[r], 1);
            g_csrp[g_rowstart[r] + pos] = make_int2(c, __float_as_int(-nr * w * nc));
            return;
        }
    }

    __shared__ ushort_t xs[64 * PADK];

    const int tid = threadIdx.x;
    const int lane = tid & 63;
    const int wv = tid >> 6;
    const int m0 = blockIdx.x * 64;
    const int n0 = m0 & (N_NODES - 1);
    const int s  = m0 >> 11;            // b*T_out + t (uniform in block)
    const int b  = s / T_out;
    const int t  = s - b * T_out;

#pragma unroll
    for (int ks = 0; ks < 3; ++ks) {
        if constexpr (LAYER == 1) {
            const bool isbf = (gam[0] == BF16_ONES_PAIR);
            const size_t elo = ((size_t)(b * T_in + t + ks) * N_NODES + n0) * 32;
            if (isbf) {
                const ushort4* src = (const ushort4*)((const ushort_t*)Xraw + elo);
                for (int i = tid; i < 512; i += 256) {
                    ushort4 v = src[i];
                    int row = i >> 3, c4 = i & 7;
                    *(ushort4*)&xs[row * PADK + ks * 32 + c4 * 4] = v;
                }
            } else {
                const float4* src = (const float4*)((const float*)Xraw + elo);
                for (int i = tid; i < 512; i += 256) {
                    float4 f = src[i];
                    ushort4 v;
                    v.x = f2bf(f.x); v.y = f2bf(f.y); v.z = f2bf(f.z); v.w = f2bf(f.w);
                    int row = i >> 3, c4 = i & 7;
                    *(ushort4*)&xs[row * PADK + ks * 32 + c4 * 4] = v;
                }
            }
        } else {
            const ushort4* src = (const ushort4*)(g_t2b +
                ((size_t)(b * T_in + t + ks) * N_NODES + n0) * 64);
            for (int i = tid; i < 1024; i += 256) {
                ushort4 v = src[i];
                int row = i >> 4, c4 = i & 15;
                *(ushort4*)&xs[row * PADK + ks * 64 + c4 * 4] = v;
            }
        }
    }
    __syncthreads();

    const ushort_t* WB = (LAYER == 1) ? g_wb1 : g_wb2;
    f32x4 acc[3][4];
#pragma unroll
    for (int st = 0; st < 3; ++st)
#pragma unroll
        for (int nt = 0; nt < 4; ++nt) acc[st][nt] = (f32x4){0.f, 0.f, 0.f, 0.f};

    const int arow = wv * 16 + (lane & 15);
    const int kofs = (lane >> 4) * 8;
#pragma unroll
    for (int kk = 0; kk < KST; ++kk) {
        bf16x8 av = *(const bf16x8*)&xs[arow * PADK + kk * 32 + kofs];
#pragma unroll
        for (int st = 0; st < 3; ++st)
#pragma unroll
            for (int nt = 0; nt < 4; ++nt) {
                bf16x8 bv = ((const bf16x8*)WB)[((st * 4 + nt) * KST + kk) * 64 + lane];
                acc[st][nt] = __builtin_amdgcn_mfma_f32_16x16x32_bf16(av, bv, acc[st][nt], 0, 0, 0);
            }
    }

    const int col = lane & 15;
    const int quad = lane >> 4;
#pragma unroll
    for (int nt = 0; nt < 4; ++nt) {
        int o = nt * 16 + col;
        float b1 = bfu(g_can[OB1 + o]);
        float b2 = bfu(g_can[OB2 + o]);
        float b3 = bfu(g_can[OB3 + o]);
#pragma unroll
        for (int reg = 0; reg < 4; ++reg) {
            int m = m0 + wv * 16 + quad * 4 + reg;
            float q = acc[1][nt][reg] + b2;
            float v = (acc[0][nt][reg] + b1) + 1.f / (1.f + expf(-q)) + (acc[2][nt][reg] + b3);
            v = v > 0.f ? v : 0.f;
            if constexpr (LAYER == 1) g_t1b[(size_t)m * 64 + o] = f2bf(v);
            else                      g_t3 [(size_t)m * 64 + o] = v;
        }
    }
}

// ---------------- graph propagation: 4-edge unroll (R15-proven), 7 slices/wave ----------------
// MODE 0 additionally re-zeros deg/cnt/cur for the next launch (blocks 0..7;
// stream-ordered after the scatter in tconv1, and prop never reads them).
template <int MODE>
__global__ __launch_bounds__(256) void prop_kernel() {
    const ushort_t* __restrict__ src = (MODE == 0) ? g_t1b : g_tx1b;
    ushort_t* __restrict__ dst = (MODE == 0) ? g_tx1b : g_tx2b;
    const int n = blockIdx.x;
    const int c = threadIdx.x & 63;
    const int sg = threadIdx.x >> 6;
    const int beg = g_rowstart[n], end = g_rowstart[n + 1];
    const int s0 = sg * 7;

    if constexpr (MODE == 0) {
        if (blockIdx.x < 8) {
            int z = blockIdx.x * 256 + threadIdx.x;
            g_deg[z] = 0.f; g_cnt[z] = 0; g_cur[z] = 0;
        }
    }

    float acc[7];
#pragma unroll
    for (int j = 0; j < 7; ++j) acc[j] = 0.f;

    int e = beg;
    for (; e + 4 <= end; e += 4) {
        int2 p0 = g_csrp[e];
        int2 p1 = g_csrp[e + 1];
        int2 p2 = g_csrp[e + 2];
        int2 p3 = g_csrp[e + 3];
        float w0 = __int_as_float(p0.y);
        float w1 = __int_as_float(p1.y);
        float w2 = __int_as_float(p2.y);
        float w3 = __int_as_float(p3.y);
        size_t b0 = ((size_t)p0.x << 6) + c;
        size_t b1 = ((size_t)p1.x << 6) + c;
        size_t b2 = ((size_t)p2.x << 6) + c;
        size_t b3 = ((size_t)p3.x << 6) + c;
#pragma unroll
        for (int j = 0; j < 7; ++j) {
            size_t so = (size_t)(s0 + j) * (N_NODES * 64);
            float v0 = bfu(src[so + b0]);
            float v1 = bfu(src[so + b1]);
            float v2 = bfu(src[so + b2]);
            float v3 = bfu(src[so + b3]);
            acc[j] = fmaf(w0, v0, fmaf(w1, v1, fmaf(w2, v2, fmaf(w3, v3, acc[j]))));
        }
    }
    for (; e + 2 <= end; e += 2) {
        int2 p0 = g_csrp[e];
        int2 p1 = g_csrp[e + 1];
        float w0 = __int_as_float(p0.y);
        float w1 = __int_as_float(p1.y);
        size_t b0 = ((size_t)p0.x << 6) + c;
        size_t b1 = ((size_t)p1.x << 6) + c;
#pragma unroll
        for (int j = 0; j < 7; ++j) {
            size_t so = (size_t)(s0 + j) * (N_NODES * 64);
            float v0 = bfu(src[so + b0]);
            float v1 = bfu(src[so + b1]);
            acc[j] = fmaf(w1, v1, fmaf(w0, v0, acc[j]));
        }
    }
    if (e < end) {
        int2 p0 = g_csrp[e];
        float w0 = __int_as_float(p0.y);
        size_t b0 = ((size_t)p0.x << 6) + c;
#pragma unroll
        for (int j = 0; j < 7; ++j)
            acc[j] = fmaf(w0, bfu(src[(size_t)(s0 + j) * (N_NODES * 64) + b0]), acc[j]);
    }

#pragma unroll
    for (int j = 0; j < 7; ++j) {
        size_t off = ((size_t)(s0 + j) * N_NODES + n) * 64 + c;
        if constexpr (MODE == 0) dst[off] = f2bf(acc[j]);
        else                     dst[off] = f2bf(2.f * acc[j] - bfu(g_t1b[off]));
    }
}

// ---------------- Cheb combine via MFMA (64-row blocks — R12-proven) ----------------
__global__ __launch_bounds__(256) void cheb_mfma_kernel() {
    constexpr int PADK = 200;
    __shared__ ushort_t xs[64 * PADK];

    const int tid = threadIdx.x;
    const int lane = tid & 63;
    const int wv = tid >> 6;
    const int m0 = blockIdx.x * 64;

#pragma unroll
    for (int sec = 0; sec < 3; ++sec) {
        const ushort_t* sp = (sec == 0) ? g_t1b : (sec == 1) ? g_tx1b : g_tx2b;
        const ushort4* src = (const ushort4*)(sp + (size_t)m0 * 64);
        for (int i = tid; i < 1024; i += 256) {
            ushort4 v = src[i];
            int row = i >> 4, c4 = i & 15;
            *(ushort4*)&xs[row * PADK + sec * 64 + c4 * 4] = v;
        }
    }
    __syncthreads();

    f32x4 acc[4];
#pragma unroll
    for (int nt = 0; nt < 4; ++nt) acc[nt] = (f32x4){0.f, 0.f, 0.f, 0.f};

    const int arow = wv * 16 + (lane & 15);
    const int kofs = (lane >> 4) * 8;
#pragma unroll
    for (int kk = 0; kk < 6; ++kk) {
        bf16x8 av = *(const bf16x8*)&xs[arow * PADK + kk * 32 + kofs];
#pragma unroll
        for (int nt = 0; nt < 4; ++nt) {
            bf16x8 bv = ((const bf16x8*)g_wbc)[(nt * 6 + kk) * 64 + lane];
            acc[nt] = __builtin_amdgcn_mfma_f32_16x16x32_bf16(av, bv, acc[nt], 0, 0, 0);
        }
    }

    const int col = lane & 15;
    const int quad = lane >> 4;
#pragma unroll
    for (int nt = 0; nt < 4; ++nt) {
        int o = nt * 16 + col;
        float bias = bfu(g_can[OFS_CHB + o]);
#pragma unroll
        for (int reg = 0; reg < 4; ++reg) {
            int m = m0 + wv * 16 + quad * 4 + reg;
            float v = acc[nt][reg] + bias;
            g_t2b[(size_t)m * 64 + o] = f2bf(v > 0.f ? v : 0.f);
        }
    }
}

// ---------------- BatchNorm: stats + apply in ONE kernel, float4 I/O (R15-proven) ----------------
__global__ __launch_bounds__(256) void bn_fused_kernel(void* __restrict__ outp,
                                                       const unsigned* __restrict__ gam) {
    int n = blockIdx.x;
    int tid = threadIdx.x;
    int q = tid & 15;
    int g = tid >> 4;
    const bool two = (g < 8);

    size_t base0 = ((size_t)(g * N_NODES + n)) * 64 + q * 4;
    float4 v0 = *reinterpret_cast<const float4*>(&g_t3[base0]);
    float s1 = v0.x + v0.y + v0.z + v0.w;
    float s2 = v0.x * v0.x + v0.y * v0.y + v0.z * v0.z + v0.w * v0.w;
    size_t base1 = 0;
    float4 v1 = make_float4(0.f, 0.f, 0.f, 0.f);
    if (two) {
        base1 = ((size_t)((g + 16) * N_NODES + n)) * 64 + q * 4;
        v1 = *reinterpret_cast<const float4*>(&g_t3[base1]);
        s1 += v1.x + v1.y + v1.z + v1.w;
        s2 += v1.x * v1.x + v1.y * v1.y + v1.z * v1.z + v1.w * v1.w;
    }

    __shared__ float r1[256], r2[256];
    __shared__ float sc_s, sh_s;
    r1[tid] = s1;
    r2[tid] = s2;
    __syncthreads();
    for (int st = 128; st > 0; st >>= 1) {
        if (tid < st) { r1[tid] += r1[tid + st]; r2[tid] += r2[tid + st]; }
        __syncthreads();
    }
    if (tid == 0) {
        const float inv = 1.f / 1536.f;
        float mean = r1[0] * inv;
        float var  = r2[0] * inv - mean * mean;
        float rstd = rsqrtf(var + 1e-5f);
        float gm = bfu(g_can[OFS_GAM + n]), be = bfu(g_can[OFS_BET + n]);
        sc_s = rstd * gm;
        sh_s = be - mean * rstd * gm;
    }
    __syncthreads();
    float sc = sc_s, sh = sh_s;
    bool isbf = (gam[0] == BF16_ONES_PAIR);

    if (isbf) {
        ushort4 o0;
        o0.x = f2bf(v0.x * sc + sh); o0.y = f2bf(v0.y * sc + sh);
        o0.z = f2bf(v0.z * sc + sh); o0.w = f2bf(v0.w * sc + sh);
        *reinterpret_cast<ushort4*>((ushort_t*)outp + base0) = o0;
        if (two) {
            ushort4 o1;
            o1.x = f2bf(v1.x * sc + sh); o1.y = f2bf(v1.y * sc + sh);
            o1.z = f2bf(v1.z * sc + sh); o1.w = f2bf(v1.w * sc + sh);
            *reinterpret_cast<ushort4*>((ushort_t*)outp + base1) = o1;
        }
    } else {
        float4 o0 = make_float4(v0.x * sc + sh, v0.y * sc + sh, v0.z * sc + sh, v0.w * sc + sh);
        *reinterpret_cast<float4*>((float*)outp + base0) = o0;
        if (two) {
            float4 o1 = make_float4(v1.x * sc + sh, v1.y * sc + sh, v1.z * sc + sh, v1.w * sc + sh);
            *reinterpret_cast<float4*>((float*)outp + base1) = o1;
        }
    }
}

// ---------------- launch (8 dispatches) ----------------
extern "C" void kernel_launch(void* const* d_in, const int* in_sizes, int n_in,
                              void* d_out, int out_size, void* d_ws, size_t ws_size,
                              hipStream_t stream) {
    const void* X = d_in[0];
    const int* ei = (const int*)d_in[1];
    const void* ew = d_in[2];
    const unsigned* gam = (const unsigned*)d_in[17];

    SmallPtrs sp;
    for (int i = 0; i < 16; ++i) sp.p[i] = d_in[3 + i];
    WPtrs wp;
    wp.p[0] = d_in[3];  wp.p[1] = d_in[5];  wp.p[2] = d_in[7];    // tc1 w1..w3
    wp.p[3] = d_in[11]; wp.p[4] = d_in[13]; wp.p[5] = d_in[15];   // tc2 w1..w3
    wp.p[6] = d_in[9];                                            // cheb_w

    setup_a_kernel<<<674, 256, 0, stream>>>(ei, ew, sp, wp, gam); // count + convert + repack
    scan_kernel<<<1, 256, 0, stream>>>();

    tconv_mfma_kernel<1><<<1024, 256, 0, stream>>>(X, ei, ew, gam); // tconv1 + edge scatter

    prop_kernel<0><<<N_NODES, 256, 0, stream>>>();                // Tx1 = L t1 (+ re-zero)
    prop_kernel<1><<<N_NODES, 256, 0, stream>>>();                // Tx2 = 2 L Tx1 - t1
    cheb_mfma_kernel<<<896, 256, 0, stream>>>();                  // t2 = relu(sum Tx_k W_k + b)

    tconv_mfma_kernel<2><<<768, 256, 0, stream>>>(X, nullptr, nullptr, gam); // t2 -> t3 fp32

    bn_fused_kernel<<<N_NODES, 256, 0, stream>>>(d_out, gam);
}